// Round 1
// baseline (145.663 us; speedup 1.0000x reference)
//
#include <hip/hip_runtime.h>
#include <hip/hip_bf16.h>
#include <math.h>

// x: (B=16, S=512, T=64, F=256) fp32.  rows = B*S = 8192, tile = T*F = 16384 floats.
// out[row][f] = sum_t softmax_t( sum_f' x[row][t][f'] * wq[row][f'] ) * x[row][t][f]
// wq[row][f]  = sum_d W[f][d] * x[row][63][d]

#define TT 64
#define FF 256
#define R1 16   // queries per block in wq kernel

// ---------------- kernel 1: wq = W @ q for all rows ----------------
__global__ __launch_bounds__(256) void wq_kernel(const float* __restrict__ x,
                                                 const float* __restrict__ W,
                                                 float* __restrict__ wq) {
    __shared__ float q[R1][FF];
    const int tid = threadIdx.x;
    const int r0  = blockIdx.x * R1;

    // stage R1 query rows (last timestep of each tile), coalesced float4
    for (int i = tid; i < R1 * (FF / 4); i += 256) {
        int g  = i >> 6;        // query row within block
        int d4 = i & 63;        // float4 index
        float4 v = *reinterpret_cast<const float4*>(
            x + (size_t)(r0 + g) * (TT * FF) + (size_t)(TT - 1) * FF + d4 * 4);
        *reinterpret_cast<float4*>(&q[g][d4 * 4]) = v;
    }
    __syncthreads();

    const int f = tid;                       // each thread owns one output feature
    float acc[R1];
#pragma unroll
    for (int g = 0; g < R1; ++g) acc[g] = 0.f;

    const float* wrow = W + (size_t)f * FF;  // W row f, contiguous in d
    for (int d0 = 0; d0 < FF; d0 += 4) {
        float4 wv = *reinterpret_cast<const float4*>(wrow + d0);
#pragma unroll
        for (int g = 0; g < R1; ++g) {
            float4 qv = *reinterpret_cast<const float4*>(&q[g][d0]);  // broadcast, conflict-free
            acc[g] += wv.x * qv.x + wv.y * qv.y + wv.z * qv.z + wv.w * qv.w;
        }
    }
#pragma unroll
    for (int g = 0; g < R1; ++g)
        wq[(size_t)(r0 + g) * FF + f] = acc[g];
}

// ---------------- core per-row attention (x read once into registers) ----------------
__device__ __forceinline__ void attn_row(const float* __restrict__ xt,
                                         float4 wqv,
                                         float* __restrict__ out_row,
                                         int tid) {
    const int lane = tid & 63;
    const int w    = tid >> 6;   // wave 0..3, owns t = 16w .. 16w+15

    __shared__ float sc[TT];
    __shared__ float part[4][FF];

    // load 16 x rows for this wave: lane l holds f = 4l..4l+3 of each row (coalesced 1KB/row)
    float4 xv[16];
#pragma unroll
    for (int j = 0; j < 16; ++j)
        xv[j] = *reinterpret_cast<const float4*>(
            xt + (size_t)(w * 16 + j) * FF + 4 * lane);

    // scores: per-row dot product, 64-lane butterfly reduce
#pragma unroll
    for (int j = 0; j < 16; ++j) {
        float s = xv[j].x * wqv.x + xv[j].y * wqv.y + xv[j].z * wqv.z + xv[j].w * wqv.w;
#pragma unroll
        for (int off = 32; off > 0; off >>= 1)
            s += __shfl_xor(s, off, 64);
        if (lane == 0) sc[w * 16 + j] = s;
    }
    __syncthreads();

    // softmax stats, computed redundantly per thread (LDS broadcast reads are free)
    float m = -INFINITY;
#pragma unroll
    for (int t = 0; t < TT; ++t) m = fmaxf(m, sc[t]);
    float l = 0.f;
#pragma unroll
    for (int t = 0; t < TT; ++t) l += __expf(sc[t] - m);

    // weighted accumulation of this wave's 16 rows, straight from registers
    float4 acc = make_float4(0.f, 0.f, 0.f, 0.f);
#pragma unroll
    for (int j = 0; j < 16; ++j) {
        float wt = __expf(sc[w * 16 + j] - m);
        acc.x += wt * xv[j].x;
        acc.y += wt * xv[j].y;
        acc.z += wt * xv[j].z;
        acc.w += wt * xv[j].w;
    }
    *reinterpret_cast<float4*>(&part[w][4 * lane]) = acc;
    __syncthreads();

    // cross-wave reduce + normalize; thread tid owns feature f = tid
    float v = part[0][tid] + part[1][tid] + part[2][tid] + part[3][tid];
    out_row[tid] = v / l;
}

// ---------------- kernel 2: fused scores + softmax + output (wq precomputed) ----------------
__global__ __launch_bounds__(256) void attn_kernel(const float* __restrict__ x,
                                                   const float* __restrict__ wq,
                                                   float* __restrict__ out) {
    const int row = blockIdx.x;
    const int tid = threadIdx.x;
    const int lane = tid & 63;
    const float* xt = x + (size_t)row * (TT * FF);

    float4 wqv = *reinterpret_cast<const float4*>(wq + (size_t)row * FF + 4 * lane);
    attn_row(xt, wqv, out + (size_t)row * FF, tid);
}

// ---------------- fallback: fully fused (wq computed per block from L2-resident W) ----------------
__global__ __launch_bounds__(256) void fused_kernel(const float* __restrict__ x,
                                                    const float* __restrict__ W,
                                                    float* __restrict__ out) {
    const int row = blockIdx.x;
    const int tid = threadIdx.x;
    const int lane = tid & 63;
    const float* xt = x + (size_t)row * (TT * FF);

    __shared__ float q[FF];
    __shared__ float wqs[FF];
    if (tid < 64) {
        float4 v = *reinterpret_cast<const float4*>(xt + (size_t)(TT - 1) * FF + tid * 4);
        *reinterpret_cast<float4*>(&q[tid * 4]) = v;
    }
    __syncthreads();

    float a = 0.f;
    const float* wrow = W + (size_t)tid * FF;
    for (int d0 = 0; d0 < FF; d0 += 4) {
        float4 wv = *reinterpret_cast<const float4*>(wrow + d0);
        float4 qv = *reinterpret_cast<const float4*>(&q[d0]);
        a += wv.x * qv.x + wv.y * qv.y + wv.z * qv.z + wv.w * qv.w;
    }
    wqs[tid] = a;
    __syncthreads();

    float4 wqv = *reinterpret_cast<const float4*>(&wqs[4 * lane]);
    attn_row(xt, wqv, out + (size_t)row * FF, tid);
}

extern "C" void kernel_launch(void* const* d_in, const int* in_sizes, int n_in,
                              void* d_out, int out_size, void* d_ws, size_t ws_size,
                              hipStream_t stream) {
    (void)n_in; (void)out_size;
    const float* x = (const float*)d_in[0];
    const float* W = (const float*)d_in[1];
    float* out = (float*)d_out;

    const int rows = in_sizes[0] / (TT * FF);   // 8192
    const size_t wq_bytes = (size_t)rows * FF * sizeof(float);

    if (ws_size >= wq_bytes) {
        float* wq = (float*)d_ws;
        wq_kernel<<<rows / R1, 256, 0, stream>>>(x, W, wq);
        attn_kernel<<<rows, 256, 0, stream>>>(x, wq, out);
    } else {
        fused_kernel<<<rows, 256, 0, stream>>>(x, W, out);
    }
}

// Round 2
// 141.792 us; speedup vs baseline: 1.0273x; 1.0273x over previous
//
#include <hip/hip_runtime.h>
#include <hip/hip_bf16.h>
#include <math.h>

// x: (B=16, S=512, T=64, F=256) fp32.  rows = B*S = 8192, tile = T*F = 16384 floats.
// out[row][f] = sum_t softmax_t( sum_f' x[row][t][f'] * wq[row][f'] ) * x[row][t][f]
// wq[row][f]  = sum_d W[f][d] * x[row][63][d]

#define TT 64
#define FF 256
#define R1 8    // queries per block in wq kernel

// ---------------- kernel 1: wq = W @ q for all rows ----------------
__global__ __launch_bounds__(256) void wq_kernel(const float* __restrict__ x,
                                                 const float* __restrict__ W,
                                                 float* __restrict__ wq) {
    __shared__ float q[R1][FF];
    const int tid = threadIdx.x;
    const int r0  = blockIdx.x * R1;

    // stage R1 query rows (last timestep of each tile), coalesced float4
    for (int i = tid; i < R1 * (FF / 4); i += 256) {
        int g  = i >> 6;        // query row within block
        int d4 = i & 63;        // float4 index
        float4 v = *reinterpret_cast<const float4*>(
            x + (size_t)(r0 + g) * (TT * FF) + (size_t)(TT - 1) * FF + d4 * 4);
        *reinterpret_cast<float4*>(&q[g][d4 * 4]) = v;
    }
    __syncthreads();

    const int f = tid;                       // each thread owns one output feature
    float acc[R1];
#pragma unroll
    for (int g = 0; g < R1; ++g) acc[g] = 0.f;

    const float* wrow = W + (size_t)f * FF;  // W row f, contiguous in d
    for (int d0 = 0; d0 < FF; d0 += 4) {
        float4 wv = *reinterpret_cast<const float4*>(wrow + d0);
#pragma unroll
        for (int g = 0; g < R1; ++g) {
            float4 qv = *reinterpret_cast<const float4*>(&q[g][d0]);  // broadcast, conflict-free
            acc[g] += wv.x * qv.x + wv.y * qv.y + wv.z * qv.z + wv.w * qv.w;
        }
    }
#pragma unroll
    for (int g = 0; g < R1; ++g)
        wq[(size_t)(r0 + g) * FF + f] = acc[g];
}

// ---------------- core per-row attention (x read once into registers) ----------------
// Fold-reduce: 16 independent 64-lane sums in 17 shuffles. After it, lane l
// holds the FULL score of wave-row (l>>2)&15 (each row duplicated in 4 lanes).
__device__ __forceinline__ void attn_row(const float* __restrict__ xt,
                                         float4 wqv,
                                         float* __restrict__ out_row,
                                         int tid) {
    const int lane = tid & 63;
    const int w    = tid >> 6;   // wave 0..3, owns t = 16w .. 16w+15

    __shared__ float sc[TT];
    __shared__ float mbuf[4];
    __shared__ float lbuf[4];
    __shared__ float part[4][FF];

    // load 16 x rows for this wave: lane l holds f = 4l..4l+3 of each row (coalesced 1KB/row)
    float4 xv[16];
#pragma unroll
    for (int j = 0; j < 16; ++j)
        xv[j] = *reinterpret_cast<const float4*>(
            xt + (size_t)(w * 16 + j) * FF + 4 * lane);

    // per-lane partial dot for each of the 16 rows
    float p[16];
#pragma unroll
    for (int j = 0; j < 16; ++j)
        p[j] = xv[j].x * wqv.x + xv[j].y * wqv.y + xv[j].z * wqv.z + xv[j].w * wqv.w;

    // ---- fold-reduce across 64 lanes (17 shuffles total) ----
    const bool b5 = (lane & 32) != 0;
    const bool b4 = (lane & 16) != 0;
    const bool b3 = (lane & 8) != 0;
    const bool b2 = (lane & 4) != 0;

    float s8[8];
#pragma unroll
    for (int j = 0; j < 8; ++j) {
        float send = b5 ? p[j] : p[j + 8];          // send what partner keeps
        float recv = __shfl_xor(send, 32, 64);
        s8[j] = (b5 ? p[j + 8] : p[j]) + recv;      // row = 8*b5 + j
    }
    float s4[4];
#pragma unroll
    for (int j = 0; j < 4; ++j) {
        float send = b4 ? s8[j] : s8[j + 4];
        float recv = __shfl_xor(send, 16, 64);
        s4[j] = (b4 ? s8[j + 4] : s8[j]) + recv;    // row = 8*b5 + 4*b4 + j
    }
    float s2[2];
#pragma unroll
    for (int j = 0; j < 2; ++j) {
        float send = b3 ? s4[j] : s4[j + 2];
        float recv = __shfl_xor(send, 8, 64);
        s2[j] = (b3 ? s4[j + 2] : s4[j]) + recv;    // row = 8*b5 + 4*b4 + 2*b3 + j
    }
    {
        float send = b2 ? s2[0] : s2[1];
        float recv = __shfl_xor(send, 4, 64);
        s2[0] = (b2 ? s2[1] : s2[0]) + recv;        // row = (lane>>2)&15, partial over bits1..0
    }
    float y = s2[0];
    y += __shfl_xor(y, 2, 64);
    y += __shfl_xor(y, 1, 64);                      // full score of row (lane>>2)&15

    // wave-local max over its 16 rows (reduce over lane bits 2..5)
    float mw = y;
    mw = fmaxf(mw, __shfl_xor(mw, 4, 64));
    mw = fmaxf(mw, __shfl_xor(mw, 8, 64));
    mw = fmaxf(mw, __shfl_xor(mw, 16, 64));
    mw = fmaxf(mw, __shfl_xor(mw, 32, 64));

    if ((lane & 3) == 0) sc[w * 16 + (lane >> 2)] = y;
    if (lane == 0) mbuf[w] = mw;
    __syncthreads();

    // global max
    float m = fmaxf(fmaxf(mbuf[0], mbuf[1]), fmaxf(mbuf[2], mbuf[3]));

    // softmax weights for this wave's 16 rows (registers; 16 exp per thread)
    float wt[16];
    float lw = 0.f;
#pragma unroll
    for (int j = 0; j < 16; ++j) {
        wt[j] = __expf(sc[w * 16 + j] - m);
        lw += wt[j];
    }

    // weighted accumulation straight from registers
    float4 acc = make_float4(0.f, 0.f, 0.f, 0.f);
#pragma unroll
    for (int j = 0; j < 16; ++j) {
        acc.x += wt[j] * xv[j].x;
        acc.y += wt[j] * xv[j].y;
        acc.z += wt[j] * xv[j].z;
        acc.w += wt[j] * xv[j].w;
    }
    *reinterpret_cast<float4*>(&part[w][4 * lane]) = acc;
    if (lane == 0) lbuf[w] = lw;
    __syncthreads();

    // cross-wave reduce + normalize; thread tid owns feature f = tid
    float l = lbuf[0] + lbuf[1] + lbuf[2] + lbuf[3];
    float v = part[0][tid] + part[1][tid] + part[2][tid] + part[3][tid];
    out_row[tid] = v / l;
}

// ---------------- kernel 2: fused scores + softmax + output (wq precomputed) ----------------
__global__ __launch_bounds__(256) void attn_kernel(const float* __restrict__ x,
                                                   const float* __restrict__ wq,
                                                   float* __restrict__ out) {
    const int row = blockIdx.x;
    const int tid = threadIdx.x;
    const int lane = tid & 63;
    const float* xt = x + (size_t)row * (TT * FF);

    float4 wqv = *reinterpret_cast<const float4*>(wq + (size_t)row * FF + 4 * lane);
    attn_row(xt, wqv, out + (size_t)row * FF, tid);
}

// ---------------- fallback: fully fused (wq computed per block from L2-resident W) ----------------
__global__ __launch_bounds__(256) void fused_kernel(const float* __restrict__ x,
                                                    const float* __restrict__ W,
                                                    float* __restrict__ out) {
    const int row = blockIdx.x;
    const int tid = threadIdx.x;
    const int lane = tid & 63;
    const float* xt = x + (size_t)row * (TT * FF);

    __shared__ float q[FF];
    __shared__ float wqs[FF];
    if (tid < 64) {
        float4 v = *reinterpret_cast<const float4*>(xt + (size_t)(TT - 1) * FF + tid * 4);
        *reinterpret_cast<float4*>(&q[tid * 4]) = v;
    }
    __syncthreads();

    float a = 0.f;
    const float* wrow = W + (size_t)tid * FF;
    for (int d0 = 0; d0 < FF; d0 += 4) {
        float4 wv = *reinterpret_cast<const float4*>(wrow + d0);
        float4 qv = *reinterpret_cast<const float4*>(&q[d0]);
        a += wv.x * qv.x + wv.y * qv.y + wv.z * qv.z + wv.w * qv.w;
    }
    wqs[tid] = a;
    __syncthreads();

    float4 wqv = *reinterpret_cast<const float4*>(&wqs[4 * lane]);
    attn_row(xt, wqv, out + (size_t)row * FF, tid);
}

extern "C" void kernel_launch(void* const* d_in, const int* in_sizes, int n_in,
                              void* d_out, int out_size, void* d_ws, size_t ws_size,
                              hipStream_t stream) {
    (void)n_in; (void)out_size;
    const float* x = (const float*)d_in[0];
    const float* W = (const float*)d_in[1];
    float* out = (float*)d_out;

    const int rows = in_sizes[0] / (TT * FF);   // 8192
    const size_t wq_bytes = (size_t)rows * FF * sizeof(float);

    if (ws_size >= wq_bytes) {
        float* wq = (float*)d_ws;
        wq_kernel<<<rows / R1, 256, 0, stream>>>(x, W, wq);
        attn_kernel<<<rows, 256, 0, stream>>>(x, wq, out);
    } else {
        fused_kernel<<<rows, 256, 0, stream>>>(x, W, out);
    }
}